// Round 1
// baseline (1494.326 us; speedup 1.0000x reference)
//
#include <hip/hip_runtime.h>
#include <hip/hip_bf16.h>

// ---------- types ----------
typedef __bf16 bf16x8_t __attribute__((ext_vector_type(8)));
typedef float f32x4_t __attribute__((ext_vector_type(4)));

#define GLDS(gp, lp) __builtin_amdgcn_global_load_lds(                        \
    (const __attribute__((address_space(1))) void*)(gp),                      \
    (__attribute__((address_space(3))) void*)(lp), 16, 0, 0)

// ---------- fast tanh (abs err ~1e-7, fine vs bf16 storage) ----------
__device__ __forceinline__ float fast_tanh(float z) {
  float zc = fminf(10.0f, fmaxf(-10.0f, z));
  float e = __expf(2.0f * zc);
  return 1.0f - 2.0f / (e + 1.0f);
}

// ---------- 1) feats[b, d*16+k] = tanh((x[b,d]-centers[d,k])*scales[d,k]) ----------
__global__ __launch_bounds__(256) void feats_kernel(
    const float* __restrict__ x, const float* __restrict__ c,
    const float* __restrict__ s, __hip_bfloat16* __restrict__ out) {
  int idx = blockIdx.x * 256 + threadIdx.x;  // (b,d) pair; 4096*1024 total
  int d = idx & 1023;
  float xv = x[idx];
  const float4* c4 = (const float4*)(c + d * 16);
  const float4* s4 = (const float4*)(s + d * 16);
  alignas(16) __hip_bfloat16 tmp[16];
#pragma unroll
  for (int g = 0; g < 4; ++g) {
    float4 cc = c4[g], ss = s4[g];
    tmp[g * 4 + 0] = __float2bfloat16(fast_tanh((xv - cc.x) * ss.x));
    tmp[g * 4 + 1] = __float2bfloat16(fast_tanh((xv - cc.y) * ss.y));
    tmp[g * 4 + 2] = __float2bfloat16(fast_tanh((xv - cc.z) * ss.z));
    tmp[g * 4 + 3] = __float2bfloat16(fast_tanh((xv - cc.w) * ss.w));
  }
  uint4* dst = (uint4*)(out + (size_t)idx * 16);
  const uint4* srcp = (const uint4*)tmp;
  dst[0] = srcp[0];
  dst[1] = srcp[1];
}

// ---------- 2) transpose fp32 [R][C] -> bf16 [C][R] ----------
__global__ __launch_bounds__(256) void transpose_to_bf16(
    const float* __restrict__ src, __hip_bfloat16* __restrict__ dst, int R, int C) {
  __shared__ float tile[32][33];
  int c0 = blockIdx.x * 32, r0 = blockIdx.y * 32;
  int tx = threadIdx.x, ty = threadIdx.y;
#pragma unroll
  for (int i = ty; i < 32; i += 8)
    tile[i][tx] = src[(size_t)(r0 + i) * C + c0 + tx];
  __syncthreads();
#pragma unroll
  for (int i = ty; i < 32; i += 8)
    dst[(size_t)(c0 + i) * R + r0 + tx] = __float2bfloat16(tile[tx][i]);
}

// ---------- 3) transpose fp32 [R][C] -> bf16 [Cpad][R] with zero pad rows ----------
__global__ __launch_bounds__(256) void transpose_pad_to_bf16(
    const float* __restrict__ src, __hip_bfloat16* __restrict__ dst,
    int R, int C, int Cpad) {
  __shared__ float tile[32][33];
  int c0 = blockIdx.x * 32, r0 = blockIdx.y * 32;
  int tx = threadIdx.x, ty = threadIdx.y;
#pragma unroll
  for (int i = ty; i < 32; i += 8) {
    int cc = c0 + tx;
    tile[i][tx] = (cc < C) ? src[(size_t)(r0 + i) * C + cc] : 0.0f;
  }
  __syncthreads();
#pragma unroll
  for (int i = ty; i < 32; i += 8) {
    int dr = c0 + i;
    if (dr < Cpad) dst[(size_t)dr * R + r0 + tx] = __float2bfloat16(tile[tx][i]);
  }
}

// ---------- 4) bf16 GEMM, B transposed ([N][K]) input, m97-style ----------
// EPI==0: out_bf16[m*N+n] = bf16(sigmoid(acc + bias[n]))
// EPI==1: out_f32[m*ncols+n] = acc + bias[n], stores only n < ncols
template <int EPI>
__global__ __launch_bounds__(256) void gemm_bt(
    const __hip_bfloat16* __restrict__ A, const __hip_bfloat16* __restrict__ Bt,
    const float* __restrict__ bias, float* __restrict__ outf,
    __hip_bfloat16* __restrict__ outb, int M, int N, int K, int ncols) {
  __shared__ __hip_bfloat16 As[128 * 32];  // [row][k], 8 KB
  __shared__ __hip_bfloat16 Bs[128 * 32];  // [n][k],   8 KB
  const int tid = threadIdx.x;
  const int wave = tid >> 6, lane = tid & 63;
  const int wm = (wave >> 1) * 64, wn = (wave & 1) * 64;
  const int gm0 = blockIdx.y * 128, gn0 = blockIdx.x * 128;

  // staging: chunk t (16 B = 8 bf16) -> row t>>2, col (t&3)*8; lds byte t*16
  const int t1 = tid, t2 = tid + 256;
  const __hip_bfloat16* Ag0 = A + (size_t)(gm0 + (t1 >> 2)) * K + (t1 & 3) * 8;
  const __hip_bfloat16* Ag1 = A + (size_t)(gm0 + (t2 >> 2)) * K + (t2 & 3) * 8;
  const __hip_bfloat16* Bg0 = Bt + (size_t)(gn0 + (t1 >> 2)) * K + (t1 & 3) * 8;
  const __hip_bfloat16* Bg1 = Bt + (size_t)(gn0 + (t2 >> 2)) * K + (t2 & 3) * 8;
  __hip_bfloat16* lA0 = As + wave * 512;
  __hip_bfloat16* lA1 = As + 2048 + wave * 512;
  __hip_bfloat16* lB0 = Bs + wave * 512;
  __hip_bfloat16* lB1 = Bs + 2048 + wave * 512;

  f32x4_t acc[4][4] = {};

  const int fr = lane & 15;        // m (A) / n (B) within 16-tile
  const int fk = (lane >> 4) * 8;  // k offset within 32

  for (int k0 = 0; k0 < K; k0 += 32) {
    GLDS(Ag0, lA0);
    GLDS(Ag1, lA1);
    GLDS(Bg0, lB0);
    GLDS(Bg1, lB1);
    Ag0 += 32; Ag1 += 32; Bg0 += 32; Bg1 += 32;
    __syncthreads();
    bf16x8_t a[4], b[4];
#pragma unroll
    for (int i = 0; i < 4; ++i) {
      a[i] = *(const bf16x8_t*)(As + (wm + i * 16 + fr) * 32 + fk);
      b[i] = *(const bf16x8_t*)(Bs + (wn + i * 16 + fr) * 32 + fk);
    }
#pragma unroll
    for (int i = 0; i < 4; ++i)
#pragma unroll
      for (int j = 0; j < 4; ++j)
        acc[i][j] = __builtin_amdgcn_mfma_f32_16x16x32_bf16(a[i], b[j], acc[i][j], 0, 0, 0);
    __syncthreads();
  }

  // C/D layout: row = (lane>>4)*4 + reg, col = lane&15
  const int cn = lane & 15, cm = (lane >> 4) * 4;
#pragma unroll
  for (int j = 0; j < 4; ++j) {
    int n = gn0 + wn + j * 16 + cn;
    float bv = (EPI == 1) ? ((n < ncols) ? bias[n] : 0.0f) : bias[n];
#pragma unroll
    for (int i = 0; i < 4; ++i) {
#pragma unroll
      for (int r = 0; r < 4; ++r) {
        int m = gm0 + wm + i * 16 + cm + r;
        float v = acc[i][j][r] + bv;
        if (EPI == 0) {
          float phi = 1.0f / (1.0f + __expf(-v));
          outb[(size_t)m * N + n] = __float2bfloat16(phi);
        } else {
          if (n < ncols) outf[(size_t)m * ncols + n] = v;
        }
      }
    }
  }
}

// ---------- launch ----------
extern "C" void kernel_launch(void* const* d_in, const int* in_sizes, int n_in,
                              void* d_out, int out_size, void* d_ws, size_t ws_size,
                              hipStream_t stream) {
  const float* x = (const float*)d_in[0];        // [4096,1024]
  const float* centers = (const float*)d_in[1];  // [1024,16]
  const float* scales = (const float*)d_in[2];   // [1024,16]
  const float* Wb = (const float*)d_in[3];       // [16384,4096]
  const float* bb = (const float*)d_in[4];       // [4096]
  const float* Wh = (const float*)d_in[5];       // [4096,1000]
  const float* bh = (const float*)d_in[6];       // [1000]
  float* out = (float*)d_out;                    // [4096,1000]

  __hip_bfloat16* feats = (__hip_bfloat16*)d_ws;              // [4096][16384]
  __hip_bfloat16* Wbt = feats + (size_t)4096 * 16384;         // [4096][16384]
  __hip_bfloat16* phi = Wbt + (size_t)4096 * 16384;           // [4096][4096]
  __hip_bfloat16* Wht = phi + (size_t)4096 * 4096;            // [1024][4096]

  feats_kernel<<<dim3(16384), dim3(256), 0, stream>>>(x, centers, scales, feats);
  transpose_to_bf16<<<dim3(128, 512), dim3(32, 8), 0, stream>>>(Wb, Wbt, 16384, 4096);
  transpose_pad_to_bf16<<<dim3(32, 128), dim3(32, 8), 0, stream>>>(Wh, Wht, 4096, 1000, 1024);
  // GEMM1: h = feats @ Wb + bb ; phi = sigmoid(h)   (M=N=4096, K=16384)
  gemm_bt<0><<<dim3(32, 32), dim3(256), 0, stream>>>(feats, Wbt, bb, nullptr, phi,
                                                     4096, 4096, 16384, 4096);
  // GEMM2: logits = phi @ Wh + bh   (M=4096, N=1024 padded, K=4096, store n<1000)
  gemm_bt<1><<<dim3(8, 32), dim3(256), 0, stream>>>(phi, Wht, bh, out, nullptr,
                                                    4096, 1024, 4096, 1000);
}

// Round 2
// 1292.030 us; speedup vs baseline: 1.1566x; 1.1566x over previous
//
#include <hip/hip_runtime.h>
#include <hip/hip_bf16.h>

// ---------- types ----------
typedef __bf16 bf16x8_t __attribute__((ext_vector_type(8)));
typedef float f32x4_t __attribute__((ext_vector_type(4)));

#define GLDS(gp, lp) __builtin_amdgcn_global_load_lds(                        \
    (const __attribute__((address_space(1))) void*)(gp),                      \
    (__attribute__((address_space(3))) void*)(lp), 16, 0, 0)

// ---------- fast tanh ----------
__device__ __forceinline__ float fast_tanh(float z) {
  float zc = fminf(10.0f, fmaxf(-10.0f, z));
  float e = __expf(2.0f * zc);
  return 1.0f - 2.0f / (e + 1.0f);
}

// ---------- 1) feats[b, d*16+k] = tanh((x[b,d]-centers[d,k])*scales[d,k]) ----------
__global__ __launch_bounds__(256) void feats_kernel(
    const float* __restrict__ x, const float* __restrict__ c,
    const float* __restrict__ s, __hip_bfloat16* __restrict__ out) {
  int idx = blockIdx.x * 256 + threadIdx.x;  // (b,d) pair; 4096*1024 total
  int d = idx & 1023;
  float xv = x[idx];
  const float4* c4 = (const float4*)(c + d * 16);
  const float4* s4 = (const float4*)(s + d * 16);
  alignas(16) __hip_bfloat16 tmp[16];
#pragma unroll
  for (int g = 0; g < 4; ++g) {
    float4 cc = c4[g], ss = s4[g];
    tmp[g * 4 + 0] = __float2bfloat16(fast_tanh((xv - cc.x) * ss.x));
    tmp[g * 4 + 1] = __float2bfloat16(fast_tanh((xv - cc.y) * ss.y));
    tmp[g * 4 + 2] = __float2bfloat16(fast_tanh((xv - cc.z) * ss.z));
    tmp[g * 4 + 3] = __float2bfloat16(fast_tanh((xv - cc.w) * ss.w));
  }
  uint4* dst = (uint4*)(out + (size_t)idx * 16);
  const uint4* srcp = (const uint4*)tmp;
  dst[0] = srcp[0];
  dst[1] = srcp[1];
}

// ---------- 2) transpose+cast fp32 [R][C] -> bf16 [Cpad][R], zero-fill c>=C ----------
// 64x64 tiles, float4 reads, 16B stores.
__global__ __launch_bounds__(256) void transpose_cast(
    const float* __restrict__ src, __hip_bfloat16* __restrict__ dst,
    int R, int C, int Cpad) {
  __shared__ float tile[64][65];
  const int c0 = blockIdx.x * 64, r0 = blockIdx.y * 64;
  const int t = threadIdx.x;
  const int rr = t >> 4, cc4 = (t & 15) * 4;
#pragma unroll
  for (int p = 0; p < 4; ++p) {
    int row = rr + p * 16;
    int cbase = c0 + cc4;
    float4 v;
    if (cbase + 3 < C) {
      v = *(const float4*)(src + (size_t)(r0 + row) * C + cbase);
    } else {
      v.x = (cbase + 0 < C) ? src[(size_t)(r0 + row) * C + cbase + 0] : 0.0f;
      v.y = (cbase + 1 < C) ? src[(size_t)(r0 + row) * C + cbase + 1] : 0.0f;
      v.z = (cbase + 2 < C) ? src[(size_t)(r0 + row) * C + cbase + 2] : 0.0f;
      v.w = (cbase + 3 < C) ? src[(size_t)(r0 + row) * C + cbase + 3] : 0.0f;
    }
    tile[row][cc4 + 0] = v.x;
    tile[row][cc4 + 1] = v.y;
    tile[row][cc4 + 2] = v.z;
    tile[row][cc4 + 3] = v.w;
  }
  __syncthreads();
#pragma unroll
  for (int p = 0; p < 2; ++p) {
    int i = t + 256 * p;
    int drow = i >> 3;
    int seg = (i & 7) * 8;
    int dc = c0 + drow;
    alignas(16) __hip_bfloat16 vals[8];
#pragma unroll
    for (int j = 0; j < 8; ++j) vals[j] = __float2bfloat16(tile[seg + j][drow]);
    if (dc < Cpad)
      *(uint4*)(dst + (size_t)dc * R + r0 + seg) = *(const uint4*)vals;
  }
}

// ---------- 3) bf16 GEMM, B transposed ([N][K]) input ----------
// BK=64 as two BK=32 half-stages per barrier (m97 LDS layout per half).
// EPI==0: outb[m*N+n] = bf16(sigmoid(acc + bias[n]))
// EPI==2: outf[(bz*M + m)*N + n] = acc   (split-K partial, no bias)
template <int EPI>
__global__ __launch_bounds__(256) void gemm_bt(
    const __hip_bfloat16* __restrict__ A, const __hip_bfloat16* __restrict__ Bt,
    const float* __restrict__ bias, float* __restrict__ outf,
    __hip_bfloat16* __restrict__ outb, int M, int N, int K, int kcount) {
  __shared__ __hip_bfloat16 As[2][128 * 32];  // [half][row*32+k], 8 KB each
  __shared__ __hip_bfloat16 Bs[2][128 * 32];
  const int tid = threadIdx.x;
  const int wave = tid >> 6, lane = tid & 63;
  const int wm = (wave >> 1) * 64, wn = (wave & 1) * 64;
  const int gm0 = blockIdx.y * 128, gn0 = blockIdx.x * 128;
  const int kbeg = blockIdx.z * kcount;

  // staging per half: chunk t (16B) -> row t>>2, k-col (t&3)*8
  const int t1 = tid, t2 = tid + 256;
  const __hip_bfloat16* Ag0 = A + (size_t)(gm0 + (t1 >> 2)) * K + kbeg + (t1 & 3) * 8;
  const __hip_bfloat16* Ag1 = A + (size_t)(gm0 + (t2 >> 2)) * K + kbeg + (t2 & 3) * 8;
  const __hip_bfloat16* Bg0 = Bt + (size_t)(gn0 + (t1 >> 2)) * K + kbeg + (t1 & 3) * 8;
  const __hip_bfloat16* Bg1 = Bt + (size_t)(gn0 + (t2 >> 2)) * K + kbeg + (t2 & 3) * 8;

  f32x4_t acc[4][4] = {};

  const int fr = lane & 15;        // m (A) / n (B) within 16-tile
  const int fk = (lane >> 4) * 8;  // k offset within 32

  for (int k0 = 0; k0 < kcount; k0 += 64) {
#pragma unroll
    for (int h = 0; h < 2; ++h) {
      GLDS(Ag0 + h * 32, &As[h][t1 * 8]);
      GLDS(Ag1 + h * 32, &As[h][t2 * 8]);
      GLDS(Bg0 + h * 32, &Bs[h][t1 * 8]);
      GLDS(Bg1 + h * 32, &Bs[h][t2 * 8]);
    }
    Ag0 += 64; Ag1 += 64; Bg0 += 64; Bg1 += 64;
    __syncthreads();
#pragma unroll
    for (int h = 0; h < 2; ++h) {
      bf16x8_t a[4], b[4];
#pragma unroll
      for (int i = 0; i < 4; ++i) {
        a[i] = *(const bf16x8_t*)(&As[h][(wm + i * 16 + fr) * 32 + fk]);
        b[i] = *(const bf16x8_t*)(&Bs[h][(wn + i * 16 + fr) * 32 + fk]);
      }
#pragma unroll
      for (int i = 0; i < 4; ++i)
#pragma unroll
        for (int j = 0; j < 4; ++j)
          acc[i][j] = __builtin_amdgcn_mfma_f32_16x16x32_bf16(a[i], b[j], acc[i][j], 0, 0, 0);
    }
    __syncthreads();
  }

  // C/D layout: row = (lane>>4)*4 + reg, col = lane&15
  const int cn = lane & 15, cm = (lane >> 4) * 4;
#pragma unroll
  for (int j = 0; j < 4; ++j) {
    int n = gn0 + wn + j * 16 + cn;
    float bv = (EPI == 0) ? bias[n] : 0.0f;
#pragma unroll
    for (int i = 0; i < 4; ++i) {
#pragma unroll
      for (int r = 0; r < 4; ++r) {
        int m = gm0 + wm + i * 16 + cm + r;
        float v = acc[i][j][r] + bv;
        if (EPI == 0) {
          float phi = 1.0f / (1.0f + __expf(-v));
          outb[(size_t)m * N + n] = __float2bfloat16(phi);
        } else {
          outf[((size_t)blockIdx.z * M + m) * N + n] = v;
        }
      }
    }
  }
}

// ---------- 4) split-K reduce + bias ----------
__global__ __launch_bounds__(256) void reduce2_kernel(
    const float* __restrict__ p, const float* __restrict__ bh,
    float* __restrict__ out) {
  int n = blockIdx.x * 256 + threadIdx.x;  // 0..1023
  int m = blockIdx.y;
  if (n < 1000)
    out[(size_t)m * 1000 + n] =
        p[(size_t)m * 1024 + n] + p[(size_t)4096 * 1024 + (size_t)m * 1024 + n] + bh[n];
}

// ---------- launch ----------
extern "C" void kernel_launch(void* const* d_in, const int* in_sizes, int n_in,
                              void* d_out, int out_size, void* d_ws, size_t ws_size,
                              hipStream_t stream) {
  const float* x = (const float*)d_in[0];        // [4096,1024]
  const float* centers = (const float*)d_in[1];  // [1024,16]
  const float* scales = (const float*)d_in[2];   // [1024,16]
  const float* Wb = (const float*)d_in[3];       // [16384,4096]
  const float* bb = (const float*)d_in[4];       // [4096]
  const float* Wh = (const float*)d_in[5];       // [4096,1000]
  const float* bh = (const float*)d_in[6];       // [1000]
  float* out = (float*)d_out;                    // [4096,1000]

  __hip_bfloat16* feats = (__hip_bfloat16*)d_ws;       // [4096][16384] (134 MB)
  __hip_bfloat16* Wbt = feats + (size_t)4096 * 16384;  // [4096][16384] (134 MB)
  __hip_bfloat16* phi = Wbt + (size_t)4096 * 16384;    // [4096][4096]  (32 MB)
  __hip_bfloat16* Wht = phi + (size_t)4096 * 4096;     // [1024][4096]  (8 MB)
  float* partial = (float*)d_ws;  // [2][4096][1024] fp32 (32 MB) — aliases feats,
                                  // which is dead once GEMM1 completes.

  feats_kernel<<<dim3(16384), dim3(256), 0, stream>>>(x, centers, scales, feats);
  // Wb [16384,4096] -> Wbt [4096][16384]
  transpose_cast<<<dim3(64, 256), dim3(256), 0, stream>>>(Wb, Wbt, 16384, 4096, 4096);
  // Wh [4096,1000] -> Wht [1024][4096], rows 1000..1023 zero
  transpose_cast<<<dim3(16, 64), dim3(256), 0, stream>>>(Wh, Wht, 4096, 1000, 1024);
  // GEMM1: phi = sigmoid(feats @ Wb + bb)   (M=N=4096, K=16384)
  gemm_bt<0><<<dim3(32, 32, 1), dim3(256), 0, stream>>>(feats, Wbt, bb, nullptr, phi,
                                                        4096, 4096, 16384, 16384);
  // GEMM2 split-K: partial[z] = phi @ Wht over K-half z  (M=4096, N=1024, K=4096)
  gemm_bt<2><<<dim3(8, 32, 2), dim3(256), 0, stream>>>(phi, Wht, nullptr, partial,
                                                       nullptr, 4096, 1024, 4096, 2048);
  // out = partial[0] + partial[1] + bh   (n < 1000)
  reduce2_kernel<<<dim3(4, 4096), dim3(256), 0, stream>>>(partial, bh, out);
}

// Round 3
// 863.413 us; speedup vs baseline: 1.7307x; 1.4964x over previous
//
#include <hip/hip_runtime.h>
#include <hip/hip_bf16.h>

// ---------- types ----------
typedef __bf16 bf16x8_t __attribute__((ext_vector_type(8)));
typedef float f32x4_t __attribute__((ext_vector_type(4)));
typedef int i32x4_t __attribute__((ext_vector_type(4)));
typedef int i32x8_t __attribute__((ext_vector_type(8)));

#define GLDS(gp, lp) __builtin_amdgcn_global_load_lds(                        \
    (const __attribute__((address_space(1))) void*)(gp),                      \
    (__attribute__((address_space(3))) void*)(lp), 16, 0, 0)

// ---------- fast tanh ----------
__device__ __forceinline__ float fast_tanh(float z) {
  float zc = fminf(10.0f, fmaxf(-10.0f, z));
  float e = __expf(2.0f * zc);
  return 1.0f - 2.0f / (e + 1.0f);
}

// pack 4 floats -> 4 fp8 e4m3 bytes (HW cvt => matches MFMA format)
__device__ __forceinline__ int pack_fp8x4(float a, float b, float c, float d) {
  int w = __builtin_amdgcn_cvt_pk_fp8_f32(a, b, 0, false);
  w = __builtin_amdgcn_cvt_pk_fp8_f32(c, d, w, true);
  return w;
}

// ---------- 1) feats (fp8 e4m3): feats[b, d*16+k] = tanh((x-c)*s) ----------
__global__ __launch_bounds__(256) void feats_kernel(
    const float* __restrict__ x, const float* __restrict__ c,
    const float* __restrict__ s, unsigned char* __restrict__ out) {
  int idx = blockIdx.x * 256 + threadIdx.x;  // (b,d) pair; 4096*1024 total
  int d = idx & 1023;
  float xv = x[idx];
  const float4* c4 = (const float4*)(c + d * 16);
  const float4* s4 = (const float4*)(s + d * 16);
  int w[4];
#pragma unroll
  for (int g = 0; g < 4; ++g) {
    float4 cc = c4[g], ss = s4[g];
    float t0 = fast_tanh((xv - cc.x) * ss.x);
    float t1 = fast_tanh((xv - cc.y) * ss.y);
    float t2 = fast_tanh((xv - cc.z) * ss.z);
    float t3 = fast_tanh((xv - cc.w) * ss.w);
    w[g] = pack_fp8x4(t0, t1, t2, t3);
  }
  *(uint4*)(out + (size_t)idx * 16) = make_uint4(w[0], w[1], w[2], w[3]);
}

// ---------- 2) transpose+cast fp32 [R][C] -> fp8 [C][R] scaled by 128 ----------
__global__ __launch_bounds__(256) void transpose_fp8(
    const float* __restrict__ src, unsigned char* __restrict__ dst, int R, int C) {
  __shared__ float tile[64][65];
  const int c0 = blockIdx.x * 64, r0 = blockIdx.y * 64;
  const int t = threadIdx.x;
  const int rr = t >> 4, cc4 = (t & 15) * 4;
#pragma unroll
  for (int p = 0; p < 4; ++p) {
    int row = rr + p * 16;
    float4 v = *(const float4*)(src + (size_t)(r0 + row) * C + c0 + cc4);
    tile[row][cc4 + 0] = v.x;
    tile[row][cc4 + 1] = v.y;
    tile[row][cc4 + 2] = v.z;
    tile[row][cc4 + 3] = v.w;
  }
  __syncthreads();
  const int drow = t >> 2, seg = (t & 3) * 16;
  int w[4];
#pragma unroll
  for (int g = 0; g < 4; ++g) {
    float a = tile[seg + g * 4 + 0][drow] * 128.0f;
    float b = tile[seg + g * 4 + 1][drow] * 128.0f;
    float cc = tile[seg + g * 4 + 2][drow] * 128.0f;
    float d = tile[seg + g * 4 + 3][drow] * 128.0f;
    w[g] = pack_fp8x4(a, b, cc, d);
  }
  *(uint4*)(dst + (size_t)(c0 + drow) * R + r0 + seg) = make_uint4(w[0], w[1], w[2], w[3]);
}

// ---------- 3) transpose+cast fp32 [R][C] -> bf16 [Cpad][R], zero-fill ----------
__global__ __launch_bounds__(256) void transpose_cast(
    const float* __restrict__ src, __hip_bfloat16* __restrict__ dst,
    int R, int C, int Cpad) {
  __shared__ float tile[64][65];
  const int c0 = blockIdx.x * 64, r0 = blockIdx.y * 64;
  const int t = threadIdx.x;
  const int rr = t >> 4, cc4 = (t & 15) * 4;
#pragma unroll
  for (int p = 0; p < 4; ++p) {
    int row = rr + p * 16;
    int cbase = c0 + cc4;
    float4 v;
    if (cbase + 3 < C) {
      v = *(const float4*)(src + (size_t)(r0 + row) * C + cbase);
    } else {
      v.x = (cbase + 0 < C) ? src[(size_t)(r0 + row) * C + cbase + 0] : 0.0f;
      v.y = (cbase + 1 < C) ? src[(size_t)(r0 + row) * C + cbase + 1] : 0.0f;
      v.z = (cbase + 2 < C) ? src[(size_t)(r0 + row) * C + cbase + 2] : 0.0f;
      v.w = (cbase + 3 < C) ? src[(size_t)(r0 + row) * C + cbase + 3] : 0.0f;
    }
    tile[row][cc4 + 0] = v.x;
    tile[row][cc4 + 1] = v.y;
    tile[row][cc4 + 2] = v.z;
    tile[row][cc4 + 3] = v.w;
  }
  __syncthreads();
#pragma unroll
  for (int p = 0; p < 2; ++p) {
    int i = t + 256 * p;
    int drow = i >> 3;
    int seg = (i & 7) * 8;
    int dc = c0 + drow;
    alignas(16) __hip_bfloat16 vals[8];
#pragma unroll
    for (int j = 0; j < 8; ++j) vals[j] = __float2bfloat16(tile[seg + j][drow]);
    if (dc < Cpad)
      *(uint4*)(dst + (size_t)dc * R + r0 + seg) = *(const uint4*)vals;
  }
}

// ---------- 4) GEMM1: MX-fp8, A [M][K], Bt [N][K], K-step 128 ----------
// XOR-swizzled LDS: row r's 16B k-group g stored at slot g^(r&7).
// out: phi[m*N+n] = bf16(sigmoid(acc/128 + bias[n]))
__global__ __launch_bounds__(256) void gemm1_mx(
    const unsigned char* __restrict__ A, const unsigned char* __restrict__ Bt,
    const float* __restrict__ bias, __hip_bfloat16* __restrict__ outb,
    int M, int N, int K) {
  __shared__ unsigned char As[128 * 128];  // 16 KB
  __shared__ unsigned char Bs[128 * 128];  // 16 KB
  const int tid = threadIdx.x;
  const int wave = tid >> 6, lane = tid & 63;
  const int wm = (wave >> 1) * 64, wn = (wave & 1) * 64;
  const int gm0 = blockIdx.y * 128, gn0 = blockIdx.x * 128;

  // staging: chunk c (16B), c = p*256 + tid; lds byte c*16; row=c>>3,
  // stored slot sg=c&7 -> global k-group g = sg ^ (row&7)
  const unsigned char* ga[4];
  const unsigned char* gb[4];
  int ldso[4];
#pragma unroll
  for (int p = 0; p < 4; ++p) {
    int cch = p * 256 + tid;
    int row = cch >> 3;
    int g = (cch & 7) ^ (row & 7);
    ga[p] = A + (size_t)(gm0 + row) * K + g * 16;
    gb[p] = Bt + (size_t)(gn0 + row) * K + g * 16;
    ldso[p] = cch * 16;
  }

  f32x4_t acc[4][4] = {};
  const int fr = lane & 15, kh = lane >> 4;  // frag row; k-quarter (32B)

  for (int k0 = 0; k0 < K; k0 += 128) {
#pragma unroll
    for (int p = 0; p < 4; ++p) {
      GLDS(ga[p] + k0, As + ldso[p]);
      GLDS(gb[p] + k0, Bs + ldso[p]);
    }
    __syncthreads();
    i32x8_t a[4], b[4];
#pragma unroll
    for (int i = 0; i < 4; ++i) {
      int ra = wm + i * 16 + fr, sa = ra & 7;
      i32x4_t alo = *(const i32x4_t*)(As + ra * 128 + (((2 * kh) ^ sa) * 16));
      i32x4_t ahi = *(const i32x4_t*)(As + ra * 128 + (((2 * kh + 1) ^ sa) * 16));
      a[i] = __builtin_shufflevector(alo, ahi, 0, 1, 2, 3, 4, 5, 6, 7);
      int rb = wn + i * 16 + fr, sb = rb & 7;
      i32x4_t blo = *(const i32x4_t*)(Bs + rb * 128 + (((2 * kh) ^ sb) * 16));
      i32x4_t bhi = *(const i32x4_t*)(Bs + rb * 128 + (((2 * kh + 1) ^ sb) * 16));
      b[i] = __builtin_shufflevector(blo, bhi, 0, 1, 2, 3, 4, 5, 6, 7);
    }
#pragma unroll
    for (int i = 0; i < 4; ++i)
#pragma unroll
      for (int j = 0; j < 4; ++j)
        acc[i][j] = __builtin_amdgcn_mfma_scale_f32_16x16x128_f8f6f4(
            a[i], b[j], acc[i][j], 0, 0, 0, 0x7F7F7F7F, 0, 0x7F7F7F7F);
    __syncthreads();
  }

  // C/D: row = (lane>>4)*4 + reg, col = lane&15
  const int cn = lane & 15, cm = (lane >> 4) * 4;
#pragma unroll
  for (int j = 0; j < 4; ++j) {
    int n = gn0 + wn + j * 16 + cn;
    float bv = bias[n];
#pragma unroll
    for (int i = 0; i < 4; ++i) {
#pragma unroll
      for (int r = 0; r < 4; ++r) {
        int m = gm0 + wm + i * 16 + cm + r;
        float v = acc[i][j][r] * 0.0078125f + bv;  // /128 de-scale of Wb
        float phi = 1.0f / (1.0f + __expf(-v));
        outb[(size_t)m * N + n] = __float2bfloat16(phi);
      }
    }
  }
}

// ---------- 5) GEMM2: bf16, split-K partial; BK=64 ----------
__global__ __launch_bounds__(256) void gemm2_bt(
    const __hip_bfloat16* __restrict__ A, const __hip_bfloat16* __restrict__ Bt,
    float* __restrict__ outf, int M, int N, int K, int kcount) {
  __shared__ __hip_bfloat16 As[2][128 * 32];
  __shared__ __hip_bfloat16 Bs[2][128 * 32];
  const int tid = threadIdx.x;
  const int wave = tid >> 6, lane = tid & 63;
  const int wm = (wave >> 1) * 64, wn = (wave & 1) * 64;
  const int gm0 = blockIdx.y * 128, gn0 = blockIdx.x * 128;
  const int kbeg = blockIdx.z * kcount;

  const int t1 = tid, t2 = tid + 256;
  const __hip_bfloat16* Ag0 = A + (size_t)(gm0 + (t1 >> 2)) * K + kbeg + (t1 & 3) * 8;
  const __hip_bfloat16* Ag1 = A + (size_t)(gm0 + (t2 >> 2)) * K + kbeg + (t2 & 3) * 8;
  const __hip_bfloat16* Bg0 = Bt + (size_t)(gn0 + (t1 >> 2)) * K + kbeg + (t1 & 3) * 8;
  const __hip_bfloat16* Bg1 = Bt + (size_t)(gn0 + (t2 >> 2)) * K + kbeg + (t2 & 3) * 8;

  f32x4_t acc[4][4] = {};
  const int fr = lane & 15, fk = (lane >> 4) * 8;

  for (int k0 = 0; k0 < kcount; k0 += 64) {
#pragma unroll
    for (int h = 0; h < 2; ++h) {
      GLDS(Ag0 + h * 32, &As[h][t1 * 8]);
      GLDS(Ag1 + h * 32, &As[h][t2 * 8]);
      GLDS(Bg0 + h * 32, &Bs[h][t1 * 8]);
      GLDS(Bg1 + h * 32, &Bs[h][t2 * 8]);
    }
    Ag0 += 64; Ag1 += 64; Bg0 += 64; Bg1 += 64;
    __syncthreads();
#pragma unroll
    for (int h = 0; h < 2; ++h) {
      bf16x8_t a[4], b[4];
#pragma unroll
      for (int i = 0; i < 4; ++i) {
        a[i] = *(const bf16x8_t*)(&As[h][(wm + i * 16 + fr) * 32 + fk]);
        b[i] = *(const bf16x8_t*)(&Bs[h][(wn + i * 16 + fr) * 32 + fk]);
      }
#pragma unroll
      for (int i = 0; i < 4; ++i)
#pragma unroll
        for (int j = 0; j < 4; ++j)
          acc[i][j] = __builtin_amdgcn_mfma_f32_16x16x32_bf16(a[i], b[j], acc[i][j], 0, 0, 0);
    }
    __syncthreads();
  }

  const int cn = lane & 15, cm = (lane >> 4) * 4;
#pragma unroll
  for (int j = 0; j < 4; ++j) {
    int n = gn0 + wn + j * 16 + cn;
#pragma unroll
    for (int i = 0; i < 4; ++i)
#pragma unroll
      for (int r = 0; r < 4; ++r) {
        int m = gm0 + wm + i * 16 + cm + r;
        outf[((size_t)blockIdx.z * M + m) * N + n] = acc[i][j][r];
      }
  }
}

// ---------- 6) split-K reduce (4 slabs) + bias ----------
__global__ __launch_bounds__(256) void reduce4_kernel(
    const float* __restrict__ p, const float* __restrict__ bh,
    float* __restrict__ out) {
  int n = blockIdx.x * 256 + threadIdx.x;  // 0..1023
  int m = blockIdx.y;
  const size_t zs = (size_t)4096 * 1024;
  if (n < 1000) {
    size_t o = (size_t)m * 1024 + n;
    out[(size_t)m * 1000 + n] = p[o] + p[zs + o] + p[2 * zs + o] + p[3 * zs + o] + bh[n];
  }
}

// ---------- launch ----------
extern "C" void kernel_launch(void* const* d_in, const int* in_sizes, int n_in,
                              void* d_out, int out_size, void* d_ws, size_t ws_size,
                              hipStream_t stream) {
  const float* x = (const float*)d_in[0];        // [4096,1024]
  const float* centers = (const float*)d_in[1];  // [1024,16]
  const float* scales = (const float*)d_in[2];   // [1024,16]
  const float* Wb = (const float*)d_in[3];       // [16384,4096]
  const float* bb = (const float*)d_in[4];       // [4096]
  const float* Wh = (const float*)d_in[5];       // [4096,1000]
  const float* bh = (const float*)d_in[6];       // [1000]
  float* out = (float*)d_out;                    // [4096,1000]

  unsigned char* feats = (unsigned char*)d_ws;          // [4096][16384] fp8 (67 MB)
  unsigned char* Wbt = feats + (size_t)4096 * 16384;    // [4096][16384] fp8 (67 MB)
  __hip_bfloat16* phi = (__hip_bfloat16*)(Wbt + (size_t)4096 * 16384);  // 32 MB
  __hip_bfloat16* Wht = phi + (size_t)4096 * 4096;      // [1024][4096] bf16 (8 MB)
  float* partial = (float*)d_ws;  // [4][4096][1024] fp32 (64 MB) — aliases feats
                                  // (dead after GEMM1) within 67 MB.

  feats_kernel<<<dim3(16384), dim3(256), 0, stream>>>(x, centers, scales, feats);
  // Wb [16384,4096] fp32 -> Wbt [4096][16384] fp8 (x128)
  transpose_fp8<<<dim3(64, 256), dim3(256), 0, stream>>>(Wb, Wbt, 16384, 4096);
  // Wh [4096,1000] -> Wht [1024][4096] bf16, rows 1000..1023 zero
  transpose_cast<<<dim3(16, 64), dim3(256), 0, stream>>>(Wh, Wht, 4096, 1000, 1024);
  // GEMM1: phi = sigmoid(feats @ Wb + bb)  (M=N=4096, K=16384), MX-fp8
  gemm1_mx<<<dim3(32, 32), dim3(256), 0, stream>>>(feats, Wbt, bb, phi, 4096, 4096, 16384);
  // GEMM2 split-K=4: partial[z] = phi @ Wht over K-quarter z
  gemm2_bt<<<dim3(8, 32, 4), dim3(256), 0, stream>>>(phi, Wht, partial, 4096, 1024, 4096, 1024);
  // out = sum_z partial[z] + bh  (n < 1000)
  reduce4_kernel<<<dim3(4, 4096), dim3(256), 0, stream>>>(partial, bh, out);
}